// Round 2
// baseline (1993.908 us; speedup 1.0000x reference)
//
#include <hip/hip_runtime.h>
#include <math.h>

#define BB 4
#define CC 64
#define HH 96
#define WW 96
#define PP (HH*WW)
#define NHD 4

// ---------------- setup: fold weights ----------------
// W0[s] (192x64): qkv_w[3s] with channel-shift folded (xp[c]=x[c+1], last repeated)
// S[p]  (192x64): qkv_w[i+1] @ po_w[i], pairs i in {0,1,3,4,6,7}
// E[s]  (64x64):  prca_w[:,64s:64s+64] @ po_w[3s+2]
// beff[p] (192):  qkv_w[i+1] @ po_b[i] + qkv_b[i+1]
// biaspr (64):    prca_b + sum_s prca_w_s @ po_b[3s+2]
__global__ __launch_bounds__(256) void k_setup(
    const float* __restrict__ qkv_w, const float* __restrict__ qkv_b,
    const float* __restrict__ po_w, const float* __restrict__ po_b,
    const float* __restrict__ prca_w, const float* __restrict__ prca_b,
    float* __restrict__ W0, float* __restrict__ S, float* __restrict__ E,
    float* __restrict__ beff, float* __restrict__ biaspr) {
  int idx = blockIdx.x*256 + threadIdx.x;
  const int pairs[6] = {0,1,3,4,6,7};
  if (idx < 36864) {
    int s = idx / 12288, r = idx % 12288;
    int o = r >> 6, c = r & 63;
    const float* W = qkv_w + (size_t)(3*s)*12288;
    float v;
    if (c == 0) v = 0.f;
    else { v = W[o*64 + c-1]; if (c == 63) v += W[o*64 + 63]; }
    W0[idx] = v;
    return;
  }
  idx -= 36864;
  if (idx < 73728) {
    int p = idx / 12288, r = idx % 12288;
    int i = pairs[p];
    int o = r >> 6, c = r & 63;
    const float* Wn = qkv_w + (size_t)(i+1)*12288 + o*64;
    const float* Pw = po_w + (size_t)i*4096;
    float acc = 0.f;
    for (int m=0;m<64;m++) acc = fmaf(Wn[m], Pw[m*64 + c], acc);
    S[idx] = acc;
    return;
  }
  idx -= 73728;
  if (idx < 12288) {
    int s = idx / 4096, r = idx % 4096;
    int o = r >> 6, c = r & 63;
    const float* Pw = po_w + (size_t)(3*s+2)*4096;
    float acc = 0.f;
    for (int m=0;m<64;m++) acc = fmaf(prca_w[o*192 + s*64 + m], Pw[m*64 + c], acc);
    E[idx] = acc;
    return;
  }
  idx -= 12288;
  if (idx < 1152) {
    int p = idx / 192, o = idx % 192;
    int i = pairs[p];
    const float* Wn = qkv_w + (size_t)(i+1)*12288 + o*64;
    const float* pb = po_b + i*64;
    float acc = qkv_b[(i+1)*192 + o];
    for (int m=0;m<64;m++) acc = fmaf(Wn[m], pb[m], acc);
    beff[idx] = acc;
    return;
  }
  idx -= 1152;
  if (idx < 64) {
    float acc = prca_b[idx];
    for (int s=0;s<3;s++) {
      const float* pb = po_b + (3*s+2)*64;
      for (int m=0;m<64;m++) acc = fmaf(prca_w[idx*192 + s*64 + m], pb[m], acc);
    }
    biaspr[idx] = acc;
  }
}

// ---------------- avg pool by r (reads original x; shift folded into W0) ----------------
__global__ __launch_bounds__(256) void k_avgpool(const float* __restrict__ in, float* __restrict__ out,
                                                 int r, int Hs, int Ws) {
  int P = Hs*Ws;
  int total = BB*CC*P;
  int idx = blockIdx.x*256 + threadIdx.x;
  if (idx >= total) return;
  int p = idx % P; int bc = idx / P;
  int y = p / Ws, x = p % Ws;
  int Win = Ws*r;
  const float* ib = in + (size_t)bc*(Hs*r)*(Ws*r);
  float s = 0.f;
  for (int dy=0; dy<r; dy++)
    for (int dx=0; dx<r; dx++)
      s += ib[(y*r+dy)*Win + (x*r+dx)];
  out[idx] = s / (float)(r*r);
}

// ---------------- LDS-tiled 1x1 conv: Cin=64, arbitrary Cout multiple of 16 ----------------
// in batch base = in + (b*inRows + inOff)*P ; weights row-major [Cout][64] (+ b*wbStride)
__global__ __launch_bounds__(256) void k_conv(
    const float* __restrict__ in, int inRows, int inOff, int P,
    const float* __restrict__ w, int wbStride,
    const float* __restrict__ bias, int Cout,
    float* __restrict__ out) {
  __shared__ float xs[64][256];
  __shared__ float wl[1024];
  __shared__ float bl[16];
  int tid = threadIdx.x;
  int b = blockIdx.z;
  int p0 = blockIdx.x * 256;
  const float* inb = in + ((size_t)b*inRows + inOff)*P;
  for (int t = tid; t < 64*64; t += 256) {
    int c = t >> 6, q4 = t & 63;
    int p = p0 + q4*4;
    float4 v = make_float4(0.f,0.f,0.f,0.f);
    if (p < P) v = *(const float4*)(inb + (size_t)c*P + p);
    xs[c][q4*4+0] = v.x; xs[c][q4*4+1] = v.y; xs[c][q4*4+2] = v.z; xs[c][q4*4+3] = v.w;
  }
  const float* wb = w + (size_t)b*wbStride;
  int p = p0 + tid;
  int ogN = Cout >> 4;
  for (int og = 0; og < ogN; og++) {
    __syncthreads();
    for (int t = tid; t < 1024; t += 256) {
      int c = t >> 4, i = t & 15;
      wl[t] = wb[(size_t)(og*16+i)*64 + c];
    }
    if (tid < 16) bl[tid] = bias ? bias[og*16+tid] : 0.f;
    __syncthreads();
    float acc[16];
    #pragma unroll
    for (int i=0;i<16;i++) acc[i] = bl[i];
    #pragma unroll 4
    for (int c=0;c<64;c++) {
      float v = xs[c][tid];
      const float* wr = &wl[c*16];
      #pragma unroll
      for (int i=0;i<16;i++) acc[i] = fmaf(v, wr[i], acc[i]);
    }
    if (p < P) {
      float* ob = out + (size_t)b*Cout*P + (size_t)(og*16)*P + p;
      #pragma unroll
      for (int i=0;i<16;i++) ob[(size_t)i*P] = acc[i];
    }
  }
}

// ---------------- depthwise 3x3 dilated-2 conv, pad 2 ----------------
__global__ __launch_bounds__(256) void k_dwconv(const float* __restrict__ in, const float* __restrict__ w,
                                                const float* __restrict__ bias, float* __restrict__ out,
                                                int Cn, int Hs, int Ws) {
  int P = Hs*Ws;
  int total = BB*Cn*P;
  int idx = blockIdx.x*256 + threadIdx.x;
  if (idx >= total) return;
  int p = idx % P; int bc = idx / P;
  int ch = bc % Cn;
  int y = p / Ws, x = p % Ws;
  const float* wc = w + ch*9;
  const float* inp = in + (size_t)bc*P;
  float acc = bias[ch];
  #pragma unroll
  for (int ky=0; ky<3; ky++) {
    int yy = y + 2*(ky-1);
    if (yy < 0 || yy >= Hs) continue;
    #pragma unroll
    for (int kx=0; kx<3; kx++) {
      int xx = x + 2*(kx-1);
      if (xx < 0 || xx >= Ws) continue;
      acc = fmaf(inp[yy*Ws+xx], wc[ky*3+kx], acc);
    }
  }
  out[idx] = acc;
}

// ---------------- gram partials (16 n-slices) + fused squared-norm partials ----------------
__global__ __launch_bounds__(256) void k_gram(const float* __restrict__ d, float* __restrict__ gpart,
                                              float* __restrict__ npart, int P) {
  int bh = blockIdx.x >> 4; int kk = blockIdx.x & 15;
  int b = bh >> 2, h = bh & 3;
  int tid = threadIdx.x;
  int ci = tid >> 4, cj = tid & 15;
  __shared__ float qs[16][132], ks[16][132];
  float acc = 0.f;
  float sqq[8], sqk[8];
  #pragma unroll
  for (int it=0; it<8; it++) { sqq[it]=0.f; sqk[it]=0.f; }
  const float* qbase = d + ((size_t)b*192 +      h*16)*P;
  const float* kbase = d + ((size_t)b*192 + 64 + h*16)*P;
  for (int n0 = kk*128; n0 < P; n0 += 2048) {
    int nrem = P - n0; if (nrem > 128) nrem = 128;
    int it = 0;
    for (int t = tid; t < 2048; t += 256, it++) {
      int r = t >> 7, cc = t & 127;
      float qv = 0.f, kv = 0.f;
      if (cc < nrem) {
        qv = qbase[(size_t)r*P + n0 + cc];
        kv = kbase[(size_t)r*P + n0 + cc];
      }
      qs[r][cc] = qv; ks[r][cc] = kv;
      sqq[it] = fmaf(qv, qv, sqq[it]);
      sqk[it] = fmaf(kv, kv, sqk[it]);
    }
    __syncthreads();
    #pragma unroll 4
    for (int n=0; n<128; n++) acc = fmaf(qs[ci][n], ks[cj][n], acc);
    __syncthreads();
  }
  gpart[blockIdx.x*256 + tid] = acc;
  // reduce norms via reuse of qs/ks
  #pragma unroll
  for (int it=0; it<8; it++) {
    int r = (tid >> 7) + 2*it;
    qs[r][tid & 127] = sqq[it];
    ks[r][tid & 127] = sqk[it];
  }
  __syncthreads();
  if (tid < 32) {
    float s = 0.f;
    if (tid < 16) { for (int cc=0; cc<128; cc++) s += qs[tid][cc]; }
    else          { for (int cc=0; cc<128; cc++) s += ks[tid-16][cc]; }
    npart[blockIdx.x*32 + tid] = s;
  }
}

// ---------------- softmax + fold into per-batch matrix U = Smat @ blockdiag(attn) ----------------
__global__ __launch_bounds__(256) void k_fold(const float* __restrict__ gpart, const float* __restrict__ npart,
                                              const float* __restrict__ temp, int layer,
                                              const float* __restrict__ Smat, float* __restrict__ Uout, int Cout) {
  int b = blockIdx.x;
  int tid = threadIdx.x;
  __shared__ float attn_s[4][256];
  __shared__ float nrm[32];
  __shared__ float rowa[256], rowb[256];
  int ci = tid >> 4, cj = tid & 15;
  for (int h=0; h<4; h++) {
    int bh = b*4 + h;
    if (tid < 32) {
      float s = 0.f;
      for (int kk=0; kk<16; kk++) s += npart[(bh*16+kk)*32 + tid];
      nrm[tid] = 1.f / fmaxf(sqrtf(s), 1e-12f);
    }
    float raw = 0.f;
    for (int kk=0; kk<16; kk++) raw += gpart[(bh*16+kk)*256 + tid];
    __syncthreads();
    raw *= nrm[ci] * nrm[16+cj] * temp[layer*4 + h];
    rowa[tid] = raw; __syncthreads();
    float mx = -1e30f;
    #pragma unroll
    for (int j=0;j<16;j++) mx = fmaxf(mx, rowa[ci*16+j]);
    float e = __expf(raw - mx);
    rowb[tid] = e; __syncthreads();
    float ssum = 0.f;
    #pragma unroll
    for (int j=0;j<16;j++) ssum += rowb[ci*16+j];
    attn_s[h][tid] = e / ssum;
    __syncthreads();
  }
  int total = Cout*64;
  for (int idx = tid; idx < total; idx += 256) {
    int col = idx & 63, o = idx >> 6;
    int h = col >> 4, jj = col & 15;
    float s = 0.f;
    #pragma unroll
    for (int ci2=0; ci2<16; ci2++)
      s = fmaf(Smat[o*64 + h*16 + ci2], attn_s[h][ci2*16 + jj], s);
    Uout[(size_t)b*total + idx] = s;
  }
}

// ---------------- bilinear upsample-accumulate ----------------
__global__ __launch_bounds__(256) void k_upsample_acc(const float* __restrict__ in, float* __restrict__ out,
                                                      int Hs, int Ws) {
  int idx = blockIdx.x*256 + threadIdx.x;
  const int total = BB*CC*PP;
  if (idx >= total) return;
  int p = idx % PP; int bc = idx / PP;
  int y = p / WW, x = p % WW;
  float sy = (y + 0.5f) * ((float)Hs / (float)HH) - 0.5f;
  float sx = (x + 0.5f) * ((float)Ws / (float)WW) - 0.5f;
  int y0 = (int)floorf(sy), x0 = (int)floorf(sx);
  float fy = sy - y0, fx = sx - x0;
  int y1 = y0 + 1, x1 = x0 + 1;
  y0 = y0 < 0 ? 0 : (y0 >= Hs ? Hs-1 : y0);
  y1 = y1 < 0 ? 0 : (y1 >= Hs ? Hs-1 : y1);
  x0 = x0 < 0 ? 0 : (x0 >= Ws ? Ws-1 : x0);
  x1 = x1 < 0 ? 0 : (x1 >= Ws ? Ws-1 : x1);
  const float* ib = in + (size_t)bc*Hs*Ws;
  float v = (1.f-fy)*((1.f-fx)*ib[y0*Ws+x0] + fx*ib[y0*Ws+x1])
          +      fy *((1.f-fx)*ib[y1*Ws+x0] + fx*ib[y1*Ws+x1]);
  out[idx] += v;
}

// ---------------- fused Mamba (fast exp, padded LDS) + GN-stat atomics ----------------
__global__ __launch_bounds__(256) void k_mamba(
    const float* __restrict__ xre, const float* __restrict__ in_w,
    const float* __restrict__ cw, const float* __restrict__ cb,
    const float* __restrict__ xpw, const float* __restrict__ dtw_,
    const float* __restrict__ dtb_, const float* __restrict__ Alog,
    const float* __restrict__ Dp, const float* __restrict__ ow,
    float* __restrict__ xr, float* __restrict__ stats) {
  int tid = threadIdx.x;
  int sl = tid >> 5;
  int d  = tid & 31;
  int nb = blockIdx.x*8;
  int b = nb / PP, p0 = nb % PP;
  const float* src = xre + (size_t)b*CC*PP + p0;

  __shared__ float xs[8][68];
  __shared__ float u_s[8][4][32];
  __shared__ float dtr[8][4];
  __shared__ float Bs[8][4][16];
  __shared__ float Cs[8][4][16];
  __shared__ float os[8][68];

  for (int t = tid; t < 512; t += 256) {
    int c = t >> 3, off = t & 7;
    xs[off][c] = src[(size_t)c*PP + off];
  }
  __syncthreads();

  float xi[4], zz[4];
  #pragma unroll
  for (int t=0;t<4;t++) {
    float a = 0.f, b2 = 0.f;
    #pragma unroll
    for (int g=0; g<16; g++) {
      float v = xs[sl][t*16+g];
      a  = fmaf(v, in_w[d*16+g], a);
      b2 = fmaf(v, in_w[(32+d)*16+g], b2);
    }
    xi[t] = a; zz[t] = b2;
  }
  float u[4];
  #pragma unroll
  for (int t=0;t<4;t++) {
    float s = cb[d];
    #pragma unroll
    for (int k=0;k<4;k++) {
      int ti = t-3+k;
      if (ti >= 0) s = fmaf(xi[ti], cw[d*4+k], s);
    }
    u[t] = s / (1.f + __expf(-s));
    u_s[sl][t][d] = u[t];
  }
  __syncthreads();
  #pragma unroll
  for (int t=0;t<4;t++) {
    float s = 0.f;
    #pragma unroll
    for (int dd=0; dd<32; dd++) s = fmaf(u_s[sl][t][dd], xpw[d*32+dd], s);
    if (d == 0) dtr[sl][t] = s;
    else if (d <= 16) Bs[sl][t][d-1] = s;
    else Cs[sl][t][d-17] = s;
  }
  if (d == 0) {
    #pragma unroll
    for (int t=0;t<4;t++) {
      float s = 0.f;
      #pragma unroll
      for (int dd=0; dd<32; dd++) s = fmaf(u_s[sl][t][dd], xpw[32*32+dd], s);
      Cs[sl][t][15] = s;
    }
  }
  __syncthreads();

  float hst[16];
  #pragma unroll
  for (int s2=0;s2<16;s2++) hst[s2] = 0.f;
  float Av[16];
  #pragma unroll
  for (int s2=0;s2<16;s2++) Av[s2] = -__expf(Alog[d*16+s2]);
  float dtw = dtw_[d], dtb = dtb_[d], Dd = Dp[d];
  #pragma unroll
  for (int t=0;t<4;t++) {
    float dv = dtr[sl][t]*dtw + dtb;
    dv = (dv > 20.f) ? dv : __logf(1.f + __expf(dv));
    float y = 0.f;
    #pragma unroll
    for (int s2=0;s2<16;s2++) {
      hst[s2] = __expf(dv*Av[s2])*hst[s2] + dv*Bs[sl][t][s2]*u[t];
      y = fmaf(hst[s2], Cs[sl][t][s2], y);
    }
    y += u[t]*Dd;
    y *= zz[t] / (1.f + __expf(-zz[t]));
    u_s[sl][t][d] = y;
  }
  __syncthreads();
  {
    int g = d & 15;
    int t0 = d >> 4;
    #pragma unroll
    for (int rep=0; rep<2; rep++) {
      int t = t0 + 2*rep;
      float s = 0.f;
      #pragma unroll
      for (int dd=0; dd<32; dd++) s = fmaf(u_s[sl][t][dd], ow[g*32+dd], s);
      os[sl][t*16+g] = s;
    }
  }
  __syncthreads();
  float* dst = xr + (size_t)b*CC*PP + p0;
  float vs[2];
  {
    int k = 0;
    for (int t = tid; t < 512; t += 256, k++) {
      int c = t >> 3, off = t & 7;
      float v = os[off][c];
      dst[(size_t)c*PP + off] = v;
      vs[k] = v;
    }
  }
  // per-wave GN partial: wave w covers channels [8w, 8w+8) (+32 for k=1) -> one group per (wave,k)
  #pragma unroll
  for (int k=0;k<2;k++) {
    float s = vs[k], ss = vs[k]*vs[k];
    #pragma unroll
    for (int o=32;o>0;o>>=1) { s += __shfl_down(s,o); ss += __shfl_down(ss,o); }
    if ((tid & 63) == 0) {
      int wid = tid >> 6;
      int g = (wid >> 1) + 2*k;
      atomicAdd(&stats[(b*4+g)*2],   s);
      atomicAdd(&stats[(b*4+g)*2+1], ss);
    }
  }
}

// ---------------- normalize + affine + silu + residual ----------------
__global__ __launch_bounds__(256) void k_final(const float* __restrict__ xr, const float* __restrict__ x,
                                               const float* __restrict__ stats, const float* __restrict__ gw,
                                               const float* __restrict__ gb, float* __restrict__ out) {
  int idx = blockIdx.x*256 + threadIdx.x;
  const int total = BB*CC*PP;
  if (idx >= total) return;
  int bc = idx / PP;
  int c = bc % CC; int b = bc / CC;
  int g = c >> 4;
  const float invN = 1.f / (float)(16*PP);
  float mu = stats[(b*4+g)*2] * invN;
  float var = stats[(b*4+g)*2+1] * invN - mu*mu;
  float v = (xr[idx] - mu) * rsqrtf(var + 1e-5f) * gw[c] + gb[c];
  v = v / (1.f + __expf(-v));
  out[idx] = v + x[idx];
}

extern "C" void kernel_launch(void* const* d_in, const int* in_sizes, int n_in,
                              void* d_out, int out_size, void* d_ws, size_t ws_size,
                              hipStream_t stream) {
  const float* x      = (const float*)d_in[0];
  const float* qkv_w  = (const float*)d_in[1];
  const float* qkv_b  = (const float*)d_in[2];
  const float* dw_w   = (const float*)d_in[3];
  const float* dw_b   = (const float*)d_in[4];
  const float* po_w   = (const float*)d_in[5];
  const float* po_b   = (const float*)d_in[6];
  const float* temp   = (const float*)d_in[7];
  const float* prca_w = (const float*)d_in[8];
  const float* prca_b = (const float*)d_in[9];
  const float* m_in_w = (const float*)d_in[10];
  const float* m_cw   = (const float*)d_in[11];
  const float* m_cb   = (const float*)d_in[12];
  const float* m_xpw  = (const float*)d_in[13];
  const float* m_dtw  = (const float*)d_in[14];
  const float* m_dtb  = (const float*)d_in[15];
  const float* m_Alog = (const float*)d_in[16];
  const float* m_D    = (const float*)d_in[17];
  const float* m_ow   = (const float*)d_in[18];
  const float* gn_w   = (const float*)d_in[19];
  const float* gn_b   = (const float*)d_in[20];
  float* out = (float*)d_out;

  const size_t SZ64  = (size_t)BB*CC*PP;
  const size_t SZ192 = (size_t)BB*192*PP;
  const size_t SZP   = (size_t)BB*CC*48*48;   // pooled / tmp max

  float* ws     = (float*)d_ws;
  float* A      = ws;                 // conv out (192ch)
  float* Bf     = A + SZ192;          // dw out (192ch)
  float* prca   = Bf + SZ192;         // SZ64
  float* pool   = prca + SZ64;        // SZP
  float* tmp    = pool + SZP;         // SZP
  float* W0     = tmp + SZP;          // 3*12288
  float* S      = W0 + 36864;         // 6*12288
  float* E      = S + 73728;          // 3*4096
  float* beff   = E + 12288;          // 6*192
  float* biaspr = beff + 1152;        // 64
  float* Ub     = biaspr + 64;        // 4*12288
  float* Vb     = Ub + 49152;         // 4*4096
  float* gpart  = Vb + 16384;         // 16bh*16kk*256 = 65536
  float* npart  = gpart + 65536;      // 16bh*16kk*32 = 8192
  float* stats  = npart + 8192;       // 32
  size_t need = (size_t)(stats + 32 - ws) * sizeof(float);
  if (ws_size < need) return;

  dim3 thr(256);

  k_setup<<<dim3(485), thr, 0, stream>>>(qkv_w, qkv_b, po_w, po_b, prca_w, prca_b,
                                         W0, S, E, beff, biaspr);

  for (int s = 0; s < 3; s++) {
    int dim = 96 >> s; int P = dim*dim;
    int gx = (P + 255)/256;
    if (s > 0)
      k_avgpool<<<dim3((BB*CC*P+255)/256), thr, 0, stream>>>(x, pool, 1<<s, dim, dim);
    for (int j = 0; j < 3; j++) {
      int i = 3*s + j;
      if (j == 0)
        k_conv<<<dim3(gx,1,BB), thr, 0, stream>>>(
            (s==0) ? x : pool, 64, 0, P, W0 + s*12288, 0, qkv_b + i*192, 192, A);
      else
        k_conv<<<dim3(gx,1,BB), thr, 0, stream>>>(
            Bf, 192, 128, P, Ub, 12288, beff + (2*s + (j-1))*192, 192, A);
      k_dwconv<<<dim3((BB*192*P+255)/256), thr, 0, stream>>>(
          A, dw_w + (size_t)i*1728, dw_b + i*192, Bf, 192, dim, dim);
      k_gram<<<dim3(BB*NHD*16), thr, 0, stream>>>(Bf, gpart, npart, P);
      if (j < 2)
        k_fold<<<dim3(BB), thr, 0, stream>>>(gpart, npart, temp, i, S + (2*s+j)*12288, Ub, 192);
      else
        k_fold<<<dim3(BB), thr, 0, stream>>>(gpart, npart, temp, i, E + s*4096, Vb, 64);
    }
    if (s == 0)
      k_conv<<<dim3(gx,1,BB), thr, 0, stream>>>(Bf, 192, 128, P, Vb, 4096, biaspr, 64, prca);
    else {
      k_conv<<<dim3(gx,1,BB), thr, 0, stream>>>(Bf, 192, 128, P, Vb, 4096, nullptr, 64, tmp);
      k_upsample_acc<<<dim3((SZ64+255)/256), thr, 0, stream>>>(tmp, prca, dim, dim);
    }
  }

  float* xr = A;
  hipMemsetAsync(stats, 0, 32*sizeof(float), stream);
  k_mamba<<<dim3(BB*PP/8), thr, 0, stream>>>(
      prca, m_in_w, m_cw, m_cb, m_xpw, m_dtw, m_dtb, m_Alog, m_D, m_ow, xr, stats);
  k_final<<<dim3((SZ64+255)/256), thr, 0, stream>>>(xr, x, stats, gn_w, gn_b, out);
}

// Round 3
// 700.518 us; speedup vs baseline: 2.8463x; 2.8463x over previous
//
#include <hip/hip_runtime.h>
#include <hip/hip_bf16.h>
#include <math.h>

#define BB 4
#define CC 64
#define HH 96
#define WW 96
#define PP (HH*WW)

typedef __hip_bfloat16 bf16;
__device__ __forceinline__ float b2f(bf16 v){ return __bfloat162float(v); }
__device__ __forceinline__ bf16  f2b(float v){ return __float2bfloat16(v); }

// element offsets of each scale inside the 192-ch bf16 ping-pong buffers
__device__ __constant__ const int c_dims[3] = {96, 48, 24};
#define SOFF0 0
#define SOFF1 7077888
#define SOFF2 8847360
#define STOT  9289728

__device__ __forceinline__ void scale_decode(int bx, int& s, int& lx) {
  if (bx < 36) { s = 0; lx = bx; }
  else if (bx < 45) { s = 1; lx = bx - 36; }
  else { s = 2; lx = bx - 45; }
}
__device__ __forceinline__ int soff_of(int s) { return s==0 ? SOFF0 : (s==1 ? SOFF1 : SOFF2); }

// ---------------- setup: fold weights (unchanged from round 2) ----------------
__global__ __launch_bounds__(256) void k_setup(
    const float* __restrict__ qkv_w, const float* __restrict__ qkv_b,
    const float* __restrict__ po_w, const float* __restrict__ po_b,
    const float* __restrict__ prca_w, const float* __restrict__ prca_b,
    float* __restrict__ W0, float* __restrict__ S, float* __restrict__ E,
    float* __restrict__ beff, float* __restrict__ biaspr) {
  int idx = blockIdx.x*256 + threadIdx.x;
  const int pairs[6] = {0,1,3,4,6,7};
  if (idx < 36864) {
    int s = idx / 12288, r = idx % 12288;
    int o = r >> 6, c = r & 63;
    const float* W = qkv_w + (size_t)(3*s)*12288;
    float v;
    if (c == 0) v = 0.f;
    else { v = W[o*64 + c-1]; if (c == 63) v += W[o*64 + 63]; }
    W0[idx] = v;
    return;
  }
  idx -= 36864;
  if (idx < 73728) {
    int p = idx / 12288, r = idx % 12288;
    int i = pairs[p];
    int o = r >> 6, c = r & 63;
    const float* Wn = qkv_w + (size_t)(i+1)*12288 + o*64;
    const float* Pw = po_w + (size_t)i*4096;
    float acc = 0.f;
    for (int m=0;m<64;m++) acc = fmaf(Wn[m], Pw[m*64 + c], acc);
    S[idx] = acc;
    return;
  }
  idx -= 73728;
  if (idx < 12288) {
    int s = idx / 4096, r = idx % 4096;
    int o = r >> 6, c = r & 63;
    const float* Pw = po_w + (size_t)(3*s+2)*4096;
    float acc = 0.f;
    for (int m=0;m<64;m++) acc = fmaf(prca_w[o*192 + s*64 + m], Pw[m*64 + c], acc);
    E[idx] = acc;
    return;
  }
  idx -= 12288;
  if (idx < 1152) {
    int p = idx / 192, o = idx % 192;
    int i = pairs[p];
    const float* Wn = qkv_w + (size_t)(i+1)*12288 + o*64;
    const float* pb = po_b + i*64;
    float acc = qkv_b[(i+1)*192 + o];
    for (int m=0;m<64;m++) acc = fmaf(Wn[m], pb[m], acc);
    beff[idx] = acc;
    return;
  }
  idx -= 1152;
  if (idx < 64) {
    float acc = prca_b[idx];
    for (int s=0;s<3;s++) {
      const float* pb = po_b + (3*s+2)*64;
      for (int m=0;m<64;m++) acc = fmaf(prca_w[idx*192 + s*64 + m], pb[m], acc);
    }
    biaspr[idx] = acc;
  }
}

// ---------------- both avg pools in one launch ----------------
__global__ __launch_bounds__(256) void k_pool(const float* __restrict__ x,
                                              float* __restrict__ pool1, float* __restrict__ pool2) {
  int idx = blockIdx.x*256 + threadIdx.x;
  if (idx < 589824) {          // 48x48, r=2
    int p = idx % 2304; int bc = idx / 2304;
    int y = p / 48, xx = p % 48;
    const float* ib = x + (size_t)bc*PP;
    float s = 0.f;
    for (int dy=0; dy<2; dy++)
      for (int dx=0; dx<2; dx++)
        s += ib[(y*2+dy)*96 + xx*2+dx];
    pool1[idx] = s * 0.25f;
  } else {
    idx -= 589824;
    if (idx >= 147456) return; // 24x24, r=4
    int p = idx % 576; int bc = idx / 576;
    int y = p / 24, xx = p % 24;
    const float* ib = x + (size_t)bc*PP;
    float s = 0.f;
    for (int dy=0; dy<4; dy++)
      for (int dx=0; dx<4; dx++)
        s += ib[(y*4+dy)*96 + xx*4+dx];
    pool2[idx] = s * 0.0625f;
  }
}

// ---------------- qkv 1x1 conv (all scales batched), weights-only LDS ----------------
// grid (48, 12, BB). j==0: fp32 input (x/pool), batch-shared W0. j>=1: bf16 v-rows, per-(s,b) Ub.
__global__ __launch_bounds__(256) void k_conv(
    const float* __restrict__ x, const float* __restrict__ pool1, const float* __restrict__ pool2,
    const bf16* __restrict__ inH, const float* __restrict__ W0, const float* __restrict__ Ub,
    const float* __restrict__ qkv_b, const float* __restrict__ beff, int j,
    bf16* __restrict__ outH) {
  int s, lx; scale_decode(blockIdx.x, s, lx);
  int dim = c_dims[s]; int P = dim*dim; int so = soff_of(s);
  int og = blockIdx.y, b = blockIdx.z;
  int tid = threadIdx.x;
  __shared__ float wl[64][16];
  __shared__ float bl[16];
  const float* wsrc = (j==0) ? (W0 + (size_t)s*12288) : (Ub + (size_t)(s*4+b)*12288);
  for (int t = tid; t < 1024; t += 256) {
    int c = t >> 4, i = t & 15;
    wl[c][i] = wsrc[(size_t)(og*16+i)*64 + c];
  }
  if (tid < 16)
    bl[tid] = (j==0) ? qkv_b[(3*s)*192 + og*16 + tid] : beff[(2*s + j - 1)*192 + og*16 + tid];
  __syncthreads();
  int p = lx*256 + tid;
  if (p >= P) return;
  float acc[16];
  #pragma unroll
  for (int i=0;i<16;i++) acc[i] = bl[i];
  if (j == 0) {
    const float* src = ((s==0) ? x : (s==1 ? pool1 : pool2)) + ((size_t)b*64)*P + p;
    #pragma unroll 4
    for (int c=0;c<64;c++) {
      float v = src[(size_t)c*P];
      #pragma unroll
      for (int i=0;i<16;i++) acc[i] = fmaf(v, wl[c][i], acc[i]);
    }
  } else {
    const bf16* src = inH + so + ((size_t)b*192 + 128)*P + p;
    #pragma unroll 4
    for (int c=0;c<64;c++) {
      float v = b2f(src[(size_t)c*P]);
      #pragma unroll
      for (int i=0;i<16;i++) acc[i] = fmaf(v, wl[c][i], acc[i]);
    }
  }
  bf16* ob = outH + so + ((size_t)(b*192 + og*16))*P + p;
  #pragma unroll
  for (int i=0;i<16;i++) ob[(size_t)i*P] = f2b(acc[i]);
}

// ---------------- depthwise 3x3 dilated-2, all scales batched ----------------
__global__ __launch_bounds__(256) void k_dw(const bf16* __restrict__ inH, const float* __restrict__ dw_w,
                                            const float* __restrict__ dw_b, int j, bf16* __restrict__ outH) {
  int idx = blockIdx.x*256 + threadIdx.x;
  int s, local;
  if (idx < SOFF1) { s=0; local = idx; }
  else if (idx < SOFF2) { s=1; local = idx - SOFF1; }
  else if (idx < STOT) { s=2; local = idx - SOFF2; }
  else return;
  int dim = c_dims[s]; int P = dim*dim;
  int p = local % P; int bc = local / P;
  int ch = bc % 192;
  int y = p / dim, xx = p % dim;
  int i3 = 3*s + j;
  const float* wc = dw_w + (size_t)i3*1728 + ch*9;
  const bf16* inp = inH + (size_t)(idx - p);
  float acc = dw_b[i3*192 + ch];
  #pragma unroll
  for (int ky=0; ky<3; ky++) {
    int yy = y + 2*(ky-1);
    if (yy < 0 || yy >= dim) continue;
    #pragma unroll
    for (int kx=0; kx<3; kx++) {
      int xx2 = xx + 2*(kx-1);
      if (xx2 < 0 || xx2 >= dim) continue;
      acc = fmaf(b2f(inp[yy*dim + xx2]), wc[ky*3+kx], acc);
    }
  }
  outH[idx] = f2b(acc);
}

// ---------------- gram partials + norm partials, all scales batched ----------------
__global__ __launch_bounds__(256) void k_gram(const bf16* __restrict__ dH, float* __restrict__ gpart,
                                              float* __restrict__ npart) {
  int bx = blockIdx.x;
  int s = bx >> 8; int r = bx & 255;
  int bh = r >> 4, kk = r & 15;
  int b = bh >> 2, h = bh & 3;
  int dim = c_dims[s]; int P = dim*dim; int so = soff_of(s);
  int tid = threadIdx.x;
  int ci = tid >> 4, cj = tid & 15;
  __shared__ float qs[16][132], ks[16][132];
  float acc = 0.f;
  float sqq[8], sqk[8];
  #pragma unroll
  for (int it=0; it<8; it++) { sqq[it]=0.f; sqk[it]=0.f; }
  const bf16* qbase = dH + so + ((size_t)b*192 +      h*16)*P;
  const bf16* kbase = dH + so + ((size_t)b*192 + 64 + h*16)*P;
  for (int n0 = kk*128; n0 < P; n0 += 2048) {
    int nrem = P - n0; if (nrem > 128) nrem = 128;
    int it = 0;
    for (int t = tid; t < 2048; t += 256, it++) {
      int rr = t >> 7, cc = t & 127;
      float qv = 0.f, kv = 0.f;
      if (cc < nrem) {
        qv = b2f(qbase[(size_t)rr*P + n0 + cc]);
        kv = b2f(kbase[(size_t)rr*P + n0 + cc]);
      }
      qs[rr][cc] = qv; ks[rr][cc] = kv;
      sqq[it] = fmaf(qv, qv, sqq[it]);
      sqk[it] = fmaf(kv, kv, sqk[it]);
    }
    __syncthreads();
    #pragma unroll 4
    for (int n=0; n<128; n++) acc = fmaf(qs[ci][n], ks[cj][n], acc);
    __syncthreads();
  }
  gpart[(size_t)s*65536 + r*256 + tid] = acc;
  #pragma unroll
  for (int it=0; it<8; it++) {
    int rr = (tid >> 7) + 2*it;
    qs[rr][tid & 127] = sqq[it];
    ks[rr][tid & 127] = sqk[it];
  }
  __syncthreads();
  if (tid < 32) {
    float sv = 0.f;
    if (tid < 16) { for (int cc=0; cc<128; cc++) sv += qs[tid][cc]; }
    else          { for (int cc=0; cc<128; cc++) sv += ks[tid-16][cc]; }
    npart[(size_t)s*8192 + r*32 + tid] = sv;
  }
}

// ---------------- softmax + fold into per-(s,b) matrix ----------------
__global__ __launch_bounds__(256) void k_fold(const float* __restrict__ gpart, const float* __restrict__ npart,
                                              const float* __restrict__ temp, int j,
                                              const float* __restrict__ S, const float* __restrict__ E,
                                              float* __restrict__ Ub, float* __restrict__ Vb) {
  int sb = blockIdx.x; int s = sb >> 2; int b = sb & 3;
  int layer = 3*s + j;
  const float* Smat = (j < 2) ? (S + (size_t)(2*s+j)*12288) : (E + (size_t)s*4096);
  float* Uout = (j < 2) ? (Ub + (size_t)sb*12288) : (Vb + (size_t)sb*4096);
  int Cout = (j < 2) ? 192 : 64;
  const float* gp = gpart + (size_t)s*65536;
  const float* np = npart + (size_t)s*8192;
  int tid = threadIdx.x;
  __shared__ float attn_s[4][256];
  __shared__ float nrm[32];
  __shared__ float rowa[256], rowb[256];
  int ci = tid >> 4, cj = tid & 15;
  for (int h=0; h<4; h++) {
    int bh = b*4 + h;
    if (tid < 32) {
      float sv = 0.f;
      for (int kk=0; kk<16; kk++) sv += np[(bh*16+kk)*32 + tid];
      nrm[tid] = 1.f / fmaxf(sqrtf(sv), 1e-12f);
    }
    float raw = 0.f;
    for (int kk=0; kk<16; kk++) raw += gp[(bh*16+kk)*256 + tid];
    __syncthreads();
    raw *= nrm[ci] * nrm[16+cj] * temp[layer*4 + h];
    rowa[tid] = raw; __syncthreads();
    float mx = -1e30f;
    #pragma unroll
    for (int jj=0;jj<16;jj++) mx = fmaxf(mx, rowa[ci*16+jj]);
    float e = __expf(raw - mx);
    rowb[tid] = e; __syncthreads();
    float ssum = 0.f;
    #pragma unroll
    for (int jj=0;jj<16;jj++) ssum += rowb[ci*16+jj];
    attn_s[h][tid] = e / ssum;
    __syncthreads();
  }
  int total = Cout*64;
  for (int idx = tid; idx < total; idx += 256) {
    int col = idx & 63, o = idx >> 6;
    int h = col >> 4, jj = col & 15;
    float sv = 0.f;
    #pragma unroll
    for (int ci2=0; ci2<16; ci2++)
      sv = fmaf(Smat[o*64 + h*16 + ci2], attn_s[h][ci2*16 + jj], sv);
    Uout[idx] = sv;
  }
}

// ---------------- final per-scale 64-ch conv (writes prca / tmp1 / tmp2) ----------------
__global__ __launch_bounds__(256) void k_convP(
    const bf16* __restrict__ inH, const float* __restrict__ Vb, const float* __restrict__ biaspr,
    float* __restrict__ prca, float* __restrict__ tmp1, float* __restrict__ tmp2) {
  int s, lx; scale_decode(blockIdx.x, s, lx);
  int dim = c_dims[s]; int P = dim*dim; int so = soff_of(s);
  int og = blockIdx.y, b = blockIdx.z;
  int tid = threadIdx.x;
  __shared__ float wl[64][16];
  __shared__ float bl[16];
  const float* wsrc = Vb + (size_t)(s*4+b)*4096;
  for (int t = tid; t < 1024; t += 256) {
    int c = t >> 4, i = t & 15;
    wl[c][i] = wsrc[(size_t)(og*16+i)*64 + c];
  }
  if (tid < 16) bl[tid] = (s == 0) ? biaspr[og*16 + tid] : 0.f;
  __syncthreads();
  int p = lx*256 + tid;
  if (p >= P) return;
  float acc[16];
  #pragma unroll
  for (int i=0;i<16;i++) acc[i] = bl[i];
  const bf16* src = inH + so + ((size_t)b*192 + 128)*P + p;
  #pragma unroll 4
  for (int c=0;c<64;c++) {
    float v = b2f(src[(size_t)c*P]);
    #pragma unroll
    for (int i=0;i<16;i++) acc[i] = fmaf(v, wl[c][i], acc[i]);
  }
  float* ob = ((s==0) ? prca : (s==1 ? tmp1 : tmp2)) + ((size_t)(b*64 + og*16))*P + p;
  #pragma unroll
  for (int i=0;i<16;i++) ob[(size_t)i*P] = acc[i];
}

// ---------------- prca += up(tmp1) + up(tmp2), bilinear half-pixel clamp ----------------
__device__ __forceinline__ float bil(const float* __restrict__ ib, int dim, int y, int x, float scale) {
  float sy = (y + 0.5f) * scale - 0.5f;
  float sx = (x + 0.5f) * scale - 0.5f;
  int y0 = (int)floorf(sy), x0 = (int)floorf(sx);
  float fy = sy - y0, fx = sx - x0;
  int y1 = y0 + 1, x1 = x0 + 1;
  y0 = y0 < 0 ? 0 : (y0 >= dim ? dim-1 : y0);
  y1 = y1 < 0 ? 0 : (y1 >= dim ? dim-1 : y1);
  x0 = x0 < 0 ? 0 : (x0 >= dim ? dim-1 : x0);
  x1 = x1 < 0 ? 0 : (x1 >= dim ? dim-1 : x1);
  return (1.f-fy)*((1.f-fx)*ib[y0*dim+x0] + fx*ib[y0*dim+x1])
       +      fy *((1.f-fx)*ib[y1*dim+x0] + fx*ib[y1*dim+x1]);
}

__global__ __launch_bounds__(256) void k_upsum(const float* __restrict__ tmp1, const float* __restrict__ tmp2,
                                               float* __restrict__ prca) {
  int idx = blockIdx.x*256 + threadIdx.x;
  if (idx >= BB*CC*PP) return;
  int p = idx % PP; int bc = idx / PP;
  int y = p / WW, x = p % WW;
  prca[idx] += bil(tmp1 + (size_t)bc*2304, 48, y, x, 0.5f)
             + bil(tmp2 + (size_t)bc*576,  24, y, x, 0.25f);
}

// ---------------- fused Mamba + spread GN partials ----------------
__global__ __launch_bounds__(256) void k_mamba(
    const float* __restrict__ xre, const float* __restrict__ in_w,
    const float* __restrict__ cw, const float* __restrict__ cb,
    const float* __restrict__ xpw, const float* __restrict__ dtw_,
    const float* __restrict__ dtb_, const float* __restrict__ Alog,
    const float* __restrict__ Dp, const float* __restrict__ ow,
    float* __restrict__ xr, float* __restrict__ statsS) {
  int tid = threadIdx.x;
  int sl = tid >> 5;
  int d  = tid & 31;
  int nb = blockIdx.x*8;
  int b = nb / PP, p0 = nb % PP;
  const float* src = xre + (size_t)b*CC*PP + p0;

  __shared__ float xs[8][68];
  __shared__ float u_s[8][4][32];
  __shared__ float dtr[8][4];
  __shared__ float Bs[8][4][16];
  __shared__ float Cs[8][4][16];
  __shared__ float os[8][68];

  for (int t = tid; t < 512; t += 256) {
    int c = t >> 3, off = t & 7;
    xs[off][c] = src[(size_t)c*PP + off];
  }
  __syncthreads();

  float xi[4], zz[4];
  #pragma unroll
  for (int t=0;t<4;t++) {
    float a = 0.f, b2 = 0.f;
    #pragma unroll
    for (int g=0; g<16; g++) {
      float v = xs[sl][t*16+g];
      a  = fmaf(v, in_w[d*16+g], a);
      b2 = fmaf(v, in_w[(32+d)*16+g], b2);
    }
    xi[t] = a; zz[t] = b2;
  }
  float u[4];
  #pragma unroll
  for (int t=0;t<4;t++) {
    float s = cb[d];
    #pragma unroll
    for (int k=0;k<4;k++) {
      int ti = t-3+k;
      if (ti >= 0) s = fmaf(xi[ti], cw[d*4+k], s);
    }
    u[t] = s / (1.f + __expf(-s));
    u_s[sl][t][d] = u[t];
  }
  __syncthreads();
  #pragma unroll
  for (int t=0;t<4;t++) {
    float s = 0.f;
    #pragma unroll
    for (int dd=0; dd<32; dd++) s = fmaf(u_s[sl][t][dd], xpw[d*32+dd], s);
    if (d == 0) dtr[sl][t] = s;
    else if (d <= 16) Bs[sl][t][d-1] = s;
    else Cs[sl][t][d-17] = s;
  }
  if (d == 0) {
    #pragma unroll
    for (int t=0;t<4;t++) {
      float s = 0.f;
      #pragma unroll
      for (int dd=0; dd<32; dd++) s = fmaf(u_s[sl][t][dd], xpw[32*32+dd], s);
      Cs[sl][t][15] = s;
    }
  }
  __syncthreads();

  float hst[16];
  #pragma unroll
  for (int s2=0;s2<16;s2++) hst[s2] = 0.f;
  float Av[16];
  #pragma unroll
  for (int s2=0;s2<16;s2++) Av[s2] = -__expf(Alog[d*16+s2]);
  float dtw = dtw_[d], dtb = dtb_[d], Dd = Dp[d];
  #pragma unroll
  for (int t=0;t<4;t++) {
    float dv = dtr[sl][t]*dtw + dtb;
    dv = (dv > 20.f) ? dv : __logf(1.f + __expf(dv));
    float y = 0.f;
    #pragma unroll
    for (int s2=0;s2<16;s2++) {
      hst[s2] = __expf(dv*Av[s2])*hst[s2] + dv*Bs[sl][t][s2]*u[t];
      y = fmaf(hst[s2], Cs[sl][t][s2], y);
    }
    y += u[t]*Dd;
    y *= zz[t] / (1.f + __expf(-zz[t]));
    u_s[sl][t][d] = y;
  }
  __syncthreads();
  {
    int g = d & 15;
    int t0 = d >> 4;
    #pragma unroll
    for (int rep=0; rep<2; rep++) {
      int t = t0 + 2*rep;
      float s = 0.f;
      #pragma unroll
      for (int dd=0; dd<32; dd++) s = fmaf(u_s[sl][t][dd], ow[g*32+dd], s);
      os[sl][t*16+g] = s;
    }
  }
  __syncthreads();
  float* dst = xr + (size_t)b*CC*PP + p0;
  float vs[2];
  {
    int k = 0;
    for (int t = tid; t < 512; t += 256, k++) {
      int c = t >> 3, off = t & 7;
      float v = os[off][c];
      dst[(size_t)c*PP + off] = v;
      vs[k] = v;
    }
  }
  // spread GN partials over 64 accumulator copies to avoid same-line atomic serialization
  #pragma unroll
  for (int k=0;k<2;k++) {
    float s = vs[k], ss = vs[k]*vs[k];
    #pragma unroll
    for (int o=32;o>0;o>>=1) { s += __shfl_down(s,o); ss += __shfl_down(ss,o); }
    if ((tid & 63) == 0) {
      int wid = tid >> 6;
      int g = (wid >> 1) + 2*k;
      float* base = statsS + (blockIdx.x & 63)*32;
      atomicAdd(&base[(b*4+g)*2],   s);
      atomicAdd(&base[(b*4+g)*2+1], ss);
    }
  }
}

// ---------------- reduce the 64 spread copies ----------------
__global__ void k_gnred(const float* __restrict__ statsS, float* __restrict__ stats) {
  int tid = threadIdx.x;
  if (tid < 32) {
    float s = 0.f;
    for (int c=0;c<64;c++) s += statsS[c*32 + tid];
    stats[tid] = s;
  }
}

// ---------------- normalize + affine + silu + residual ----------------
__global__ __launch_bounds__(256) void k_final(const float* __restrict__ xr, const float* __restrict__ x,
                                               const float* __restrict__ stats, const float* __restrict__ gw,
                                               const float* __restrict__ gb, float* __restrict__ out) {
  int idx = blockIdx.x*256 + threadIdx.x;
  if (idx >= BB*CC*PP) return;
  int bc = idx / PP;
  int c = bc % CC; int b = bc / CC;
  int g = c >> 4;
  const float invN = 1.f / (float)(16*PP);
  float mu = stats[(b*4+g)*2] * invN;
  float var = stats[(b*4+g)*2+1] * invN - mu*mu;
  float v = (xr[idx] - mu) * rsqrtf(var + 1e-5f) * gw[c] + gb[c];
  v = v / (1.f + __expf(-v));
  out[idx] = v + x[idx];
}

extern "C" void kernel_launch(void* const* d_in, const int* in_sizes, int n_in,
                              void* d_out, int out_size, void* d_ws, size_t ws_size,
                              hipStream_t stream) {
  const float* x      = (const float*)d_in[0];
  const float* qkv_w  = (const float*)d_in[1];
  const float* qkv_b  = (const float*)d_in[2];
  const float* dw_w   = (const float*)d_in[3];
  const float* dw_b   = (const float*)d_in[4];
  const float* po_w   = (const float*)d_in[5];
  const float* po_b   = (const float*)d_in[6];
  const float* temp   = (const float*)d_in[7];
  const float* prca_w = (const float*)d_in[8];
  const float* prca_b = (const float*)d_in[9];
  const float* m_in_w = (const float*)d_in[10];
  const float* m_cw   = (const float*)d_in[11];
  const float* m_cb   = (const float*)d_in[12];
  const float* m_xpw  = (const float*)d_in[13];
  const float* m_dtw  = (const float*)d_in[14];
  const float* m_dtb  = (const float*)d_in[15];
  const float* m_Alog = (const float*)d_in[16];
  const float* m_D    = (const float*)d_in[17];
  const float* m_ow   = (const float*)d_in[18];
  const float* gn_w   = (const float*)d_in[19];
  const float* gn_b   = (const float*)d_in[20];
  float* out = (float*)d_out;

  // workspace carve (float units; bf16 buffers take STOT/2 floats each)
  float* ws     = (float*)d_ws;
  bf16*  AH     = (bf16*)ws;                       // STOT bf16 = 4644864 floats
  bf16*  BfH    = (bf16*)(ws + 4644864);           // STOT bf16
  float* prca   = ws + 2*4644864;                  // 2359296
  float* xr     = prca + 2359296;                  // 2359296
  float* pool1  = xr + 2359296;                    // 589824 (reused as tmp1)
  float* pool2  = pool1 + 589824;                  // 147456 (reused as tmp2)
  float* W0     = pool2 + 147456;                  // 36864
  float* S      = W0 + 36864;                      // 73728
  float* E      = S + 73728;                       // 12288
  float* beff   = E + 12288;                       // 1152
  float* biaspr = beff + 1152;                     // 64
  float* Ub     = biaspr + 64;                     // 147456
  float* Vb     = Ub + 147456;                     // 49152
  float* gpart  = Vb + 49152;                      // 196608
  float* npart  = gpart + 196608;                  // 24576
  float* statsS = npart + 24576;                   // 2048
  float* stats  = statsS + 2048;                   // 32
  size_t need = (size_t)(stats + 32 - ws) * sizeof(float);
  if (ws_size < need) return;

  dim3 thr(256);

  k_setup<<<dim3(485), thr, 0, stream>>>(qkv_w, qkv_b, po_w, po_b, prca_w, prca_b,
                                         W0, S, E, beff, biaspr);
  k_pool<<<dim3(2880), thr, 0, stream>>>(x, pool1, pool2);

  for (int j = 0; j < 3; j++) {
    k_conv<<<dim3(48, 12, BB), thr, 0, stream>>>(x, pool1, pool2, BfH, W0, Ub, qkv_b, beff, j, AH);
    k_dw<<<dim3((STOT + 255)/256), thr, 0, stream>>>(AH, dw_w, dw_b, j, BfH);
    k_gram<<<dim3(3*256), thr, 0, stream>>>(BfH, gpart, npart);
    k_fold<<<dim3(12), thr, 0, stream>>>(gpart, npart, temp, j, S, E, Ub, Vb);
  }

  k_convP<<<dim3(48, 4, BB), thr, 0, stream>>>(BfH, Vb, biaspr, prca, pool1, pool2);
  k_upsum<<<dim3((BB*CC*PP + 255)/256), thr, 0, stream>>>(pool1, pool2, prca);

  hipMemsetAsync(statsS, 0, 2048*sizeof(float), stream);
  k_mamba<<<dim3(BB*PP/8), thr, 0, stream>>>(
      prca, m_in_w, m_cw, m_cb, m_xpw, m_dtw, m_dtb, m_Alog, m_D, m_ow, xr, statsS);
  k_gnred<<<dim3(1), dim3(64), 0, stream>>>(statsS, stats);
  k_final<<<dim3((BB*CC*PP + 255)/256), thr, 0, stream>>>(xr, x, stats, gn_w, gn_b, out);
}